// Round 2
// baseline (10392.112 us; speedup 1.0000x reference)
//
#include <hip/hip_runtime.h>
#include <hip/hip_bf16.h>

// IntelligentNetwork on MI355X.
// Structure: attn [N,N] is input-independent -> compute once (bf16).
// Per step t: ctx = attn[NI:,:] @ prev  (bf16 MFMA GEMM, fp32 accum)
//             per-neuron MLPs (fp32)    -> next state (bf16, transposed layout)
//             y_t = act @ Wp^T + bp     (fp32)
// State layout ST[c][m], c = b*SIG+d, m = neuron  (both GEMM operands K-contiguous).

#define NI 128
#define NTR 3584
#define NA 384
#define NN 4096
#define NO (NN - NI)        // 3968 = 31*128
#define NACT0 (NI + NTR)    // 3712
#define HID 32
#define KQ 16
#define SIG 16
#define IN_DIM 128
#define OUT_DIM 64
#define BB 64
#define TT 32
#define CDIM (BB * SIG)     // 1024

typedef unsigned short ushort_t;
typedef __attribute__((ext_vector_type(8))) short short8v;
typedef __attribute__((ext_vector_type(4))) float f32x4;

__device__ inline ushort_t f2b(float f) {
  __hip_bfloat16 h = __float2bfloat16(f);
  return *reinterpret_cast<ushort_t*>(&h);
}

__device__ inline void gll16(const void* g, void* l) {
  __builtin_amdgcn_global_load_lds(
      (const __attribute__((address_space(1))) unsigned int*)g,
      (__attribute__((address_space(3))) unsigned int*)l, 16, 0, 0);
}

// ---------------- attention matrix (once per launch) ----------------
// A[row][m] = softmax_m( (q[NI+row] . k[m]) / 4 ), bf16.  grid: NO blocks x 256.
__global__ __launch_bounds__(256) void attn_kernel(const float* __restrict__ q_all,
                                                   const float* __restrict__ k_all,
                                                   ushort_t* __restrict__ A) {
  const int row = blockIdx.x;
  const int n = NI + row;
  float q[KQ];
#pragma unroll
  for (int i = 0; i < KQ; ++i) q[i] = q_all[n * KQ + i];

  float e[16];
  float local = 0.f;
#pragma unroll
  for (int j = 0; j < 16; ++j) {
    const int m = j * 256 + threadIdx.x;
    const float* kr = k_all + (size_t)m * KQ;
    float s = 0.f;
#pragma unroll
    for (int i = 0; i < KQ; ++i) s += q[i] * kr[i];
    e[j] = __expf(s * 0.25f);   // 1/sqrt(KQ) = 0.25
    local += e[j];
  }
  __shared__ float red[256];
  red[threadIdx.x] = local;
  __syncthreads();
  for (int off = 128; off > 0; off >>= 1) {
    if (threadIdx.x < off) red[threadIdx.x] += red[threadIdx.x + off];
    __syncthreads();
  }
  const float inv = 1.f / red[0];
#pragma unroll
  for (int j = 0; j < 16; ++j) {
    const int m = j * 256 + threadIdx.x;
    A[(size_t)row * NN + m] = f2b(e[j] * inv);
  }
}

// ---------------- per-step GEMM: ctx[NO][CDIM] = A[NO][NN] * ST^T ----------------
// m97 structure: BM=BN=128, BK=32, 4 waves (2x2), 4x4 16x16x32 frags per wave.
#define BM 128
#define BN 128
#define BK 32

__global__ __launch_bounds__(256) void gemm_kernel(const ushort_t* __restrict__ A,
                                                   const ushort_t* __restrict__ B,  // ST [CDIM][NN]
                                                   float* __restrict__ C) {         // [NO][CDIM]
  __shared__ ushort_t As[BM * BK];  // 8 KB, row-major [row][k]
  __shared__ ushort_t Bs[BN * BK];  // 8 KB, row-major [col][k]

  const int tid = threadIdx.x;
  const int wave = tid >> 6, lane = tid & 63;
  const int wr = wave >> 1, wc = wave & 1;
  const int mbase = blockIdx.x * BM;
  const int nbase = blockIdx.y * BN;

  f32x4 acc[4][4];
#pragma unroll
  for (int i = 0; i < 4; ++i)
#pragma unroll
    for (int j = 0; j < 4; ++j) acc[i][j] = (f32x4){0.f, 0.f, 0.f, 0.f};

  // staging map: chunk q in {0,1}: lds elem = q*2048 + tid*8  -> row = q*64 + tid/4, k = (tid%4)*8
  const int row0 = tid >> 2;
  const int k0 = (tid & 3) * 8;
  const ushort_t* ga0 = A + (size_t)(mbase + row0) * NN + k0;
  const ushort_t* ga1 = ga0 + (size_t)64 * NN;
  const ushort_t* gb0 = B + (size_t)(nbase + row0) * NN + k0;
  const ushort_t* gb1 = gb0 + (size_t)64 * NN;
  ushort_t* laA0 = As + wave * 512;
  ushort_t* laA1 = As + 2048 + wave * 512;
  ushort_t* laB0 = Bs + wave * 512;
  ushort_t* laB1 = Bs + 2048 + wave * 512;

  const int r = lane & 15, koff = (lane >> 4) * 8;

  for (int ks = 0; ks < NN / BK; ++ks) {
    __syncthreads();                 // previous iter's reads done before overwrite
    gll16(ga0, laA0); gll16(ga1, laA1);
    gll16(gb0, laB0); gll16(gb1, laB1);
    ga0 += BK; ga1 += BK; gb0 += BK; gb1 += BK;
    __syncthreads();                 // drains vmcnt -> staging visible

    short8v a[4], b[4];
#pragma unroll
    for (int mi = 0; mi < 4; ++mi)
      a[mi] = *(const short8v*)&As[(wr * 64 + mi * 16 + r) * BK + koff];
#pragma unroll
    for (int ni = 0; ni < 4; ++ni)
      b[ni] = *(const short8v*)&Bs[(wc * 64 + ni * 16 + r) * BK + koff];
#pragma unroll
    for (int mi = 0; mi < 4; ++mi)
#pragma unroll
      for (int ni = 0; ni < 4; ++ni)
        acc[mi][ni] = __builtin_amdgcn_mfma_f32_16x16x32_bf16(a[mi], b[ni], acc[mi][ni], 0, 0, 0);
  }

  const int r4 = (lane >> 4) * 4, cidx = lane & 15;
#pragma unroll
  for (int mi = 0; mi < 4; ++mi) {
    const int rowa = mbase + wr * 64 + mi * 16 + r4;
#pragma unroll
    for (int ni = 0; ni < 4; ++ni) {
      const int col = nbase + wc * 64 + ni * 16 + cidx;
#pragma unroll
      for (int v = 0; v < 4; ++v)
        C[(size_t)(rowa + v) * CDIM + col] = acc[mi][ni][v];
    }
  }
}

// ---------------- per-step neuron MLPs ----------------
// grid: 256 blocks x 1024 threads. block covers 16 neurons x 64 batches.
// tid = b + 64*nl  (wave-uniform neuron -> broadcast weight reads).
__global__ __launch_bounds__(1024) void neuron_kernel(
    const float* __restrict__ x, int t,
    const float* __restrict__ W1_in, const float* __restrict__ b1_in,
    const float* __restrict__ W2_in, const float* __restrict__ b2_in,
    const float* __restrict__ W1_o, const float* __restrict__ b1_o,
    const float* __restrict__ W2_o, const float* __restrict__ b2_o,
    const float* __restrict__ ctx,   // [NO][CDIM]
    ushort_t* __restrict__ STnext,   // [CDIM][NN]
    float* __restrict__ act) {       // [BB][NA*SIG]
  const int tid = threadIdx.x;
  const int b = tid & 63, nl = tid >> 6;
  const int n = blockIdx.x * 16 + nl;

  float out[SIG];
  float h[HID];

  if (n < NI) {
    const float* xb = x + ((size_t)b * TT + t) * IN_DIM;
    const float* w1 = W1_in + (size_t)n * HID * IN_DIM;
#pragma unroll
    for (int hh = 0; hh < HID; ++hh) h[hh] = b1_in[n * HID + hh];
    for (int i = 0; i < IN_DIM; i += 4) {
      const float4 xv = *(const float4*)(xb + i);
#pragma unroll
      for (int hh = 0; hh < HID; ++hh) {
        const float4 wv = *(const float4*)(w1 + hh * IN_DIM + i);
        h[hh] += wv.x * xv.x + wv.y * xv.y + wv.z * xv.z + wv.w * xv.w;
      }
    }
#pragma unroll
    for (int hh = 0; hh < HID; ++hh) h[hh] = tanhf(h[hh]);
    const float* w2 = W2_in + (size_t)n * SIG * HID;
#pragma unroll
    for (int d = 0; d < SIG; ++d) {
      float s = b2_in[n * SIG + d];
#pragma unroll
      for (int hh = 0; hh < HID; ++hh) s += w2[d * HID + hh] * h[hh];
      out[d] = s;
    }
  } else {
    const int no = n - NI;
    const float* c = ctx + (size_t)no * CDIM + b * SIG;
    float cv[SIG];
#pragma unroll
    for (int d = 0; d < SIG; ++d) cv[d] = c[d];
    const float* w1 = W1_o + (size_t)no * HID * SIG;
#pragma unroll
    for (int hh = 0; hh < HID; ++hh) {
      float s = b1_o[no * HID + hh];
#pragma unroll
      for (int d = 0; d < SIG; ++d) s += w1[hh * SIG + d] * cv[d];
      h[hh] = tanhf(s);
    }
    const float* w2 = W2_o + (size_t)no * SIG * HID;
#pragma unroll
    for (int d = 0; d < SIG; ++d) {
      float s = b2_o[no * SIG + d];
#pragma unroll
      for (int hh = 0; hh < HID; ++hh) s += w2[d * HID + hh] * h[hh];
      out[d] = s;
    }
    if (n >= NACT0) {
      float* ap = act + (size_t)b * (NA * SIG) + (n - NACT0) * SIG;
#pragma unroll
      for (int d = 0; d < SIG; ++d) ap[d] = out[d];
    }
  }

  // LDS transpose -> coalesced-ish writes of ST[c][n0..n0+16)
  __shared__ ushort_t ts[BB][SIG][16];  // [b][d][nl], 32 KB
#pragma unroll
  for (int d = 0; d < SIG; ++d) ts[b][d][nl] = f2b(out[d]);
  __syncthreads();
  const uint4* src = (const uint4*)&ts[tid >> 4][tid & 15][0];
  const uint4 v0 = src[0], v1 = src[1];
  uint4* dst = (uint4*)(STnext + (size_t)tid * NN + blockIdx.x * 16);
  dst[0] = v0; dst[1] = v1;
}

// ---------------- per-step output projection ----------------
// grid: BB blocks x 256. y[b][o] = act[b] . Wp[o] + bp[o]
__global__ __launch_bounds__(256) void proj_kernel(const float* __restrict__ act,
                                                   const float* __restrict__ Wp,
                                                   const float* __restrict__ bp,
                                                   float* __restrict__ out, int t) {
  const int b = blockIdx.x;
  const int o = threadIdx.x & 63, q = threadIdx.x >> 6;
  const float* a = act + (size_t)b * (NA * SIG) + q * 1536;
  const float* w = Wp + (size_t)o * (NA * SIG) + q * 1536;
  float s = 0.f;
  for (int j = 0; j < 1536; j += 4) {
    const float4 av = *(const float4*)(a + j);
    const float4 wv = *(const float4*)(w + j);
    s += av.x * wv.x + av.y * wv.y + av.z * wv.z + av.w * wv.w;
  }
  __shared__ float red[4][64];
  red[q][o] = s;
  __syncthreads();
  if (q == 0) {
    const float y = red[0][o] + red[1][o] + red[2][o] + red[3][o] + bp[o];
    out[((size_t)b * TT + t) * OUT_DIM + o] = y;
  }
}

extern "C" void kernel_launch(void* const* d_in, const int* in_sizes, int n_in,
                              void* d_out, int out_size, void* d_ws, size_t ws_size,
                              hipStream_t stream) {
  const float* x     = (const float*)d_in[0];
  const float* W1_in = (const float*)d_in[1];
  const float* b1_in = (const float*)d_in[2];
  const float* W2_in = (const float*)d_in[3];
  const float* b2_in = (const float*)d_in[4];
  const float* W1_o  = (const float*)d_in[5];
  const float* b1_o  = (const float*)d_in[6];
  const float* W2_o  = (const float*)d_in[7];
  const float* b2_o  = (const float*)d_in[8];
  const float* q_all = (const float*)d_in[9];
  const float* k_all = (const float*)d_in[10];
  const float* Wp    = (const float*)d_in[11];
  const float* bp    = (const float*)d_in[12];
  float* out = (float*)d_out;

  char* p = (char*)d_ws;
  ushort_t* Abf = (ushort_t*)p; p += (size_t)NO * NN * 2;      // 32.5 MB
  ushort_t* ST0 = (ushort_t*)p; p += (size_t)CDIM * NN * 2;    // 8.4 MB
  ushort_t* ST1 = (ushort_t*)p; p += (size_t)CDIM * NN * 2;    // 8.4 MB
  float*    ctx = (float*)p;    p += (size_t)NO * CDIM * 4;    // 16.3 MB
  float*    act = (float*)p;    p += (size_t)BB * NA * SIG * 4;// 1.6 MB

  hipMemsetAsync(ST0, 0, (size_t)CDIM * NN * 2, stream);       // prev0 = 0
  attn_kernel<<<NO, 256, 0, stream>>>(q_all, k_all, Abf);

  for (int t = 0; t < TT; ++t) {
    ushort_t* prev = (t & 1) ? ST1 : ST0;
    ushort_t* next = (t & 1) ? ST0 : ST1;
    dim3 grid(NO / BM, CDIM / BN);  // 31 x 8
    gemm_kernel<<<grid, 256, 0, stream>>>(Abf, prev, ctx);
    neuron_kernel<<<NN / 16, 1024, 0, stream>>>(x, t, W1_in, b1_in, W2_in, b2_in,
                                                W1_o, b1_o, W2_o, b2_o, ctx, next, act);
    proj_kernel<<<BB, 256, 0, stream>>>(act, Wp, bp, out, t);
  }
}

// Round 7
// 6901.208 us; speedup vs baseline: 1.5058x; 1.5058x over previous
//
#include <hip/hip_runtime.h>
#include <hip/hip_bf16.h>

// IntelligentNetwork on MI355X — fused step kernel.
// attn [NO,NN] is input-independent -> computed once (bf16).
// Per step t, ONE fused kernel (grid 32x8):
//   blocks bx<31 : ctx-tile = attn-tile @ ST_prev (bf16 MFMA, fp32 acc) -> LDS
//                  -> per-neuron MLP in epilogue -> bf16 state write (transposed)
//   block  bx==31: input-neuron MLP from x -> bf16 state write
// Then a small projection kernel produces y_t.
// State layout ST[c][m], c = b*SIG+d, m = neuron (both GEMM operands K-contiguous).

#define NI 128
#define NTR 3584
#define NA 384
#define NN 4096
#define NO (NN - NI)        // 3968 = 31*128
#define HID 32
#define KQ 16
#define SIG 16
#define IN_DIM 128
#define OUT_DIM 64
#define BB 64
#define TT 32
#define CDIM (BB * SIG)     // 1024

#define BM 128
#define BN 128
#define BK 32
#define CTXP 132            // padded LDS row stride (floats)

typedef unsigned short ushort_t;
typedef __attribute__((ext_vector_type(8))) short short8v;
typedef __attribute__((ext_vector_type(4))) float f32x4;

__device__ inline ushort_t f2b(float f) {
  __hip_bfloat16 h = __float2bfloat16(f);
  return *reinterpret_cast<ushort_t*>(&h);
}

__device__ inline float tanh_fast(float s) {
  // tanh(x) = 1 - 2/(e^{2x}+1); __expf is v_exp-based, rel err ~1e-6
  const float e = __expf(2.f * s);
  return 1.f - 2.f / (e + 1.f);
}

__device__ inline void gll16(const void* g, void* l) {
  __builtin_amdgcn_global_load_lds(
      (const __attribute__((address_space(1))) unsigned int*)g,
      (__attribute__((address_space(3))) unsigned int*)l, 16, 0, 0);
}

// ---------------- attention matrix (once per launch) ----------------
__global__ __launch_bounds__(256) void attn_kernel(const float* __restrict__ q_all,
                                                   const float* __restrict__ k_all,
                                                   ushort_t* __restrict__ A) {
  const int row = blockIdx.x;
  const int n = NI + row;
  float q[KQ];
#pragma unroll
  for (int i = 0; i < KQ; ++i) q[i] = q_all[n * KQ + i];

  float e[16];
  float local = 0.f;
#pragma unroll
  for (int j = 0; j < 16; ++j) {
    const int m = j * 256 + threadIdx.x;
    const float* kr = k_all + (size_t)m * KQ;
    float s = 0.f;
#pragma unroll
    for (int i = 0; i < KQ; ++i) s += q[i] * kr[i];
    e[j] = __expf(s * 0.25f);   // 1/sqrt(KQ) = 0.25
    local += e[j];
  }
  __shared__ float red[256];
  red[threadIdx.x] = local;
  __syncthreads();
  for (int off = 128; off > 0; off >>= 1) {
    if (threadIdx.x < off) red[threadIdx.x] += red[threadIdx.x + off];
    __syncthreads();
  }
  const float inv = 1.f / red[0];
#pragma unroll
  for (int j = 0; j < 16; ++j) {
    const int m = j * 256 + threadIdx.x;
    A[(size_t)row * NN + m] = f2b(e[j] * inv);
  }
}

// ---------------- fused per-step kernel ----------------
// grid (32, 8) x 256 threads. bx<31: GEMM+MLP for 128 trans/action neurons x 8 batches.
// bx==31: input-neuron MLP (128 neurons) x 8 batches.
__global__ __launch_bounds__(256) void fused_step_kernel(
    const ushort_t* __restrict__ A,     // [NO][NN] bf16 attn
    const ushort_t* __restrict__ Bst,   // ST_prev [CDIM][NN] bf16
    const float* __restrict__ x, int t,
    const float* __restrict__ W1_in, const float* __restrict__ b1_in,
    const float* __restrict__ W2_in, const float* __restrict__ b2_in,
    const float* __restrict__ W1_o, const float* __restrict__ b1_o,
    const float* __restrict__ W2_o, const float* __restrict__ b2_o,
    ushort_t* __restrict__ STnext,      // [CDIM][NN] bf16
    float* __restrict__ act) {          // [BB][NA*SIG] fp32
  __shared__ ushort_t As[BM * BK];        // 8 KB
  __shared__ ushort_t Bs[BN * BK];        // 8 KB
  __shared__ float ctxs[128 * CTXP];      // 67.6 KB

  const int tid = threadIdx.x;
  const int bx = blockIdx.x, by = blockIdx.y;
  const int nbase = by * BN;

  if (bx < 31) {
    // ---------- GEMM: 128 rows (neurons no=mbase..) x 128 cols (c=nbase..) ----------
    const int mbase = bx * BM;
    const int wave = tid >> 6, lane = tid & 63;
    const int wr = wave >> 1, wc = wave & 1;

    f32x4 acc[4][4];
#pragma unroll
    for (int i = 0; i < 4; ++i)
#pragma unroll
      for (int j = 0; j < 4; ++j) acc[i][j] = (f32x4){0.f, 0.f, 0.f, 0.f};

    const int row0 = tid >> 2;
    const int k0 = (tid & 3) * 8;
    const ushort_t* ga0 = A + (size_t)(mbase + row0) * NN + k0;
    const ushort_t* ga1 = ga0 + (size_t)64 * NN;
    const ushort_t* gb0 = Bst + (size_t)(nbase + row0) * NN + k0;
    const ushort_t* gb1 = gb0 + (size_t)64 * NN;
    ushort_t* laA0 = As + wave * 512;
    ushort_t* laA1 = As + 2048 + wave * 512;
    ushort_t* laB0 = Bs + wave * 512;
    ushort_t* laB1 = Bs + 2048 + wave * 512;

    const int r = lane & 15, koff = (lane >> 4) * 8;

    for (int ks = 0; ks < NN / BK; ++ks) {
      __syncthreads();
      gll16(ga0, laA0); gll16(ga1, laA1);
      gll16(gb0, laB0); gll16(gb1, laB1);
      ga0 += BK; ga1 += BK; gb0 += BK; gb1 += BK;
      __syncthreads();

      short8v a[4], b[4];
#pragma unroll
      for (int mi = 0; mi < 4; ++mi)
        a[mi] = *(const short8v*)&As[(wr * 64 + mi * 16 + r) * BK + koff];
#pragma unroll
      for (int ni = 0; ni < 4; ++ni)
        b[ni] = *(const short8v*)&Bs[(wc * 64 + ni * 16 + r) * BK + koff];
#pragma unroll
      for (int mi = 0; mi < 4; ++mi)
#pragma unroll
        for (int ni = 0; ni < 4; ++ni)
          acc[mi][ni] = __builtin_amdgcn_mfma_f32_16x16x32_bf16(a[mi], b[ni], acc[mi][ni], 0, 0, 0);
    }

    // acc -> LDS ctx tile (local [neuron][col])
    const int r4 = (lane >> 4) * 4, cidx = lane & 15;
#pragma unroll
    for (int mi = 0; mi < 4; ++mi)
#pragma unroll
      for (int ni = 0; ni < 4; ++ni)
#pragma unroll
        for (int v = 0; v < 4; ++v)
          ctxs[(wr * 64 + mi * 16 + r4 + v) * CTXP + wc * 64 + ni * 16 + cidx] = acc[mi][ni][v];
    __syncthreads();

    // ---------- per-neuron MLP epilogue: 128 neurons x 8 batches, 4 pairs/thread ----------
    const bool is_action = (mbase >= 3584);
    for (int iter = 0; iter < 4; ++iter) {
      const int nr = iter * 32 + (tid >> 3);   // local neuron 0..127
      const int bl = tid & 7;                  // local batch 0..7
      float cv[SIG];
      const float* cp = ctxs + nr * CTXP + bl * SIG;
#pragma unroll
      for (int d = 0; d < SIG; ++d) cv[d] = cp[d];

      const int no = mbase + nr;
      const float* w1 = W1_o + (size_t)no * HID * SIG;
      const float* b1 = b1_o + (size_t)no * HID;
      float h[HID];
#pragma unroll
      for (int hh = 0; hh < HID; ++hh) {
        float s = b1[hh];
#pragma unroll
        for (int d = 0; d < SIG; ++d) s += w1[hh * SIG + d] * cv[d];
        h[hh] = tanh_fast(s);
      }
      const float* w2 = W2_o + (size_t)no * SIG * HID;
      const float* b2 = b2_o + (size_t)no * SIG;
      float o16[SIG];
#pragma unroll
      for (int d = 0; d < SIG; ++d) {
        float s = b2[d];
#pragma unroll
        for (int hh = 0; hh < HID; ++hh) s += w2[d * HID + hh] * h[hh];
        o16[d] = s;
      }
      if (is_action) {
        float* ap = act + (size_t)(by * 8 + bl) * (NA * SIG) + (size_t)(no - 3584) * SIG;
#pragma unroll
        for (int k = 0; k < 4; ++k)
          *(float4*)(ap + 4 * k) = make_float4(o16[4*k], o16[4*k+1], o16[4*k+2], o16[4*k+3]);
      }
      float* wp = ctxs + nr * CTXP + bl * SIG;
#pragma unroll
      for (int d = 0; d < SIG; ++d) wp[d] = o16[d];
    }
    __syncthreads();
  } else {
    // ---------- input-neuron MLP: 128 neurons x 8 batches ----------
    for (int iter = 0; iter < 4; ++iter) {
      const int nr = iter * 32 + (tid >> 3);
      const int bl = tid & 7;
      const int bg = by * 8 + bl;
      const float* xb = x + ((size_t)bg * TT + t) * IN_DIM;
      const float* w1 = W1_in + (size_t)nr * HID * IN_DIM;
      float h[HID];
#pragma unroll
      for (int hh = 0; hh < HID; ++hh) h[hh] = b1_in[nr * HID + hh];
      for (int i = 0; i < IN_DIM; i += 4) {
        const float4 xv = *(const float4*)(xb + i);
#pragma unroll
        for (int hh = 0; hh < HID; ++hh) {
          const float4 wv = *(const float4*)(w1 + hh * IN_DIM + i);
          h[hh] += wv.x * xv.x + wv.y * xv.y + wv.z * xv.z + wv.w * xv.w;
        }
      }
#pragma unroll
      for (int hh = 0; hh < HID; ++hh) h[hh] = tanh_fast(h[hh]);
      const float* w2 = W2_in + (size_t)nr * SIG * HID;
      float o16[SIG];
#pragma unroll
      for (int d = 0; d < SIG; ++d) {
        float s = b2_in[nr * SIG + d];
#pragma unroll
        for (int hh = 0; hh < HID; ++hh) s += w2[d * HID + hh] * h[hh];
        o16[d] = s;
      }
      float* wp = ctxs + nr * CTXP + bl * SIG;
#pragma unroll
      for (int d = 0; d < SIG; ++d) wp[d] = o16[d];
    }
    __syncthreads();
  }

  // ---------- common write-out: ctxs (fp32, [neuron][c_local]) -> STnext bf16 ----------
  // thread: c_local = tid>>1 (0..127), half nh = tid&1 covers 64 neurons -> 128B store.
  const int col0 = (bx == 31) ? 0 : NI + bx * BM;
  const int c = tid >> 1, nh = tid & 1;
  const float* colp = ctxs + (size_t)nh * 64 * CTXP + c;
  uint4* dst = (uint4*)(STnext + (size_t)(nbase + c) * NN + col0 + nh * 64);
#pragma unroll
  for (int k = 0; k < 8; ++k) {
    const unsigned w0 = (unsigned)f2b(colp[(k*8+0)*CTXP]) | ((unsigned)f2b(colp[(k*8+1)*CTXP]) << 16);
    const unsigned w1 = (unsigned)f2b(colp[(k*8+2)*CTXP]) | ((unsigned)f2b(colp[(k*8+3)*CTXP]) << 16);
    const unsigned w2 = (unsigned)f2b(colp[(k*8+4)*CTXP]) | ((unsigned)f2b(colp[(k*8+5)*CTXP]) << 16);
    const unsigned w3 = (unsigned)f2b(colp[(k*8+6)*CTXP]) | ((unsigned)f2b(colp[(k*8+7)*CTXP]) << 16);
    dst[k] = make_uint4(w0, w1, w2, w3);
  }
}

// ---------------- per-step output projection ----------------
__global__ __launch_bounds__(256) void proj_kernel(const float* __restrict__ act,
                                                   const float* __restrict__ Wp,
                                                   const float* __restrict__ bp,
                                                   float* __restrict__ out, int t) {
  const int b = blockIdx.x;
  const int o = threadIdx.x & 63, q = threadIdx.x >> 6;
  const float* a = act + (size_t)b * (NA * SIG) + q * 1536;
  const float* w = Wp + (size_t)o * (NA * SIG) + q * 1536;
  float s = 0.f;
  for (int j = 0; j < 1536; j += 4) {
    const float4 av = *(const float4*)(a + j);
    const float4 wv = *(const float4*)(w + j);
    s += av.x * wv.x + av.y * wv.y + av.z * wv.z + av.w * wv.w;
  }
  __shared__ float red[4][64];
  red[q][o] = s;
  __syncthreads();
  if (q == 0) {
    const float y = red[0][o] + red[1][o] + red[2][o] + red[3][o] + bp[o];
    out[((size_t)b * TT + t) * OUT_DIM + o] = y;
  }
}

extern "C" void kernel_launch(void* const* d_in, const int* in_sizes, int n_in,
                              void* d_out, int out_size, void* d_ws, size_t ws_size,
                              hipStream_t stream) {
  const float* x     = (const float*)d_in[0];
  const float* W1_in = (const float*)d_in[1];
  const float* b1_in = (const float*)d_in[2];
  const float* W2_in = (const float*)d_in[3];
  const float* b2_in = (const float*)d_in[4];
  const float* W1_o  = (const float*)d_in[5];
  const float* b1_o  = (const float*)d_in[6];
  const float* W2_o  = (const float*)d_in[7];
  const float* b2_o  = (const float*)d_in[8];
  const float* q_all = (const float*)d_in[9];
  const float* k_all = (const float*)d_in[10];
  const float* Wp    = (const float*)d_in[11];
  const float* bp    = (const float*)d_in[12];
  float* out = (float*)d_out;

  char* p = (char*)d_ws;
  ushort_t* Abf = (ushort_t*)p; p += (size_t)NO * NN * 2;      // 32.5 MB
  ushort_t* ST0 = (ushort_t*)p; p += (size_t)CDIM * NN * 2;    // 8.4 MB
  ushort_t* ST1 = (ushort_t*)p; p += (size_t)CDIM * NN * 2;    // 8.4 MB
  float*    act = (float*)p;    p += (size_t)BB * NA * SIG * 4;// 1.6 MB

  hipMemsetAsync(ST0, 0, (size_t)CDIM * NN * 2, stream);       // prev0 = 0
  attn_kernel<<<NO, 256, 0, stream>>>(q_all, k_all, Abf);

  for (int t = 0; t < TT; ++t) {
    ushort_t* prev = (t & 1) ? ST1 : ST0;
    ushort_t* next = (t & 1) ? ST0 : ST1;
    dim3 grid(32, CDIM / BN);  // 32 x 8 = 256 blocks = 1/CU
    fused_step_kernel<<<grid, 256, 0, stream>>>(Abf, prev, x, t,
                                                W1_in, b1_in, W2_in, b2_in,
                                                W1_o, b1_o, W2_o, b2_o, next, act);
    proj_kernel<<<BB, 256, 0, stream>>>(act, Wp, bp, out, t);
  }
}

// Round 8
// 6142.327 us; speedup vs baseline: 1.6919x; 1.1235x over previous
//
#include <hip/hip_runtime.h>
#include <hip/hip_bf16.h>

// IntelligentNetwork on MI355X — fused step kernel, latency-optimized GEMM.
// attn [NO,NN] is input-independent -> computed once (bf16).
// Per step t, ONE fused kernel (grid 32x8):
//   blocks bx<31 : ctx-tile = attn-tile @ ST_prev (bf16 MFMA, fp32 acc) -> LDS
//                  GEMM K-loop: BK=64, explicit LDS double-buffer, raw s_barrier +
//                  vmcnt(0), next-tile global_load_lds issued AFTER the barrier so
//                  they overlap the ds_read+MFMA phase (1 block/CU -> no inter-block
//                  overlap exists; must hide latency intra-block).
//                  LDS tiles XOR-swizzled (rule-21: linear gll16 dest, inverse-swz
//                  global source, swz on read) to kill 16-way bank conflicts.
//                  -> per-neuron MLP in epilogue -> bf16 state write (transposed)
//   block  bx==31: input-neuron MLP from x -> bf16 state write
// proj reads a pre-transposed WpT for coalesced weight access.

#define NI 128
#define NTR 3584
#define NA 384
#define NN 4096
#define NO (NN - NI)        // 3968 = 31*128
#define HID 32
#define KQ 16
#define SIG 16
#define IN_DIM 128
#define OUT_DIM 64
#define BB 64
#define TT 32
#define CDIM (BB * SIG)     // 1024

#define BM 128
#define BN 128
#define BK 64
#define NKS (NN / BK)       // 64 K-steps
#define CTXP 132            // padded LDS row stride (floats)

typedef unsigned short ushort_t;
typedef __attribute__((ext_vector_type(8))) short short8v;
typedef __attribute__((ext_vector_type(4))) float f32x4;

__device__ inline ushort_t f2b(float f) {
  __hip_bfloat16 h = __float2bfloat16(f);
  return *reinterpret_cast<ushort_t*>(&h);
}

__device__ inline float tanh_fast(float s) {
  const float e = __expf(2.f * s);
  return 1.f - 2.f / (e + 1.f);
}

__device__ inline void gll16(const void* g, void* l) {
  __builtin_amdgcn_global_load_lds(
      (const __attribute__((address_space(1))) unsigned int*)g,
      (__attribute__((address_space(3))) unsigned int*)l, 16, 0, 0);
}

// ---------------- attention matrix (once per launch) ----------------
__global__ __launch_bounds__(256) void attn_kernel(const float* __restrict__ q_all,
                                                   const float* __restrict__ k_all,
                                                   ushort_t* __restrict__ A) {
  const int row = blockIdx.x;
  const int n = NI + row;
  float q[KQ];
#pragma unroll
  for (int i = 0; i < KQ; ++i) q[i] = q_all[n * KQ + i];

  float e[16];
  float local = 0.f;
#pragma unroll
  for (int j = 0; j < 16; ++j) {
    const int m = j * 256 + threadIdx.x;
    const float* kr = k_all + (size_t)m * KQ;
    float s = 0.f;
#pragma unroll
    for (int i = 0; i < KQ; ++i) s += q[i] * kr[i];
    e[j] = __expf(s * 0.25f);
    local += e[j];
  }
  __shared__ float red[256];
  red[threadIdx.x] = local;
  __syncthreads();
  for (int off = 128; off > 0; off >>= 1) {
    if (threadIdx.x < off) red[threadIdx.x] += red[threadIdx.x + off];
    __syncthreads();
  }
  const float inv = 1.f / red[0];
#pragma unroll
  for (int j = 0; j < 16; ++j) {
    const int m = j * 256 + threadIdx.x;
    A[(size_t)row * NN + m] = f2b(e[j] * inv);
  }
}

// ---------------- Wp transpose (once): WpT[j][o] = Wp[o][j] ----------------
__global__ __launch_bounds__(256) void wpt_kernel(const float* __restrict__ Wp,
                                                  float* __restrict__ WpT) {
  __shared__ float tile[64][65];
  const int j0 = blockIdx.x * 64;
  const int tx = threadIdx.x & 63, ty = threadIdx.x >> 6;  // ty 0..3
#pragma unroll
  for (int oo = ty; oo < 64; oo += 4)
    tile[oo][tx] = Wp[(size_t)oo * (NA * SIG) + j0 + tx];
  __syncthreads();
#pragma unroll
  for (int oo = ty; oo < 64; oo += 4)
    WpT[(size_t)(j0 + oo) * 64 + tx] = tile[tx][oo];
}

// ---------------- fused per-step kernel ----------------
__global__ __launch_bounds__(256) void fused_step_kernel(
    const ushort_t* __restrict__ A,     // [NO][NN] bf16 attn
    const ushort_t* __restrict__ Bst,   // ST_prev [CDIM][NN] bf16
    const float* __restrict__ x, int t,
    const float* __restrict__ W1_in, const float* __restrict__ b1_in,
    const float* __restrict__ W2_in, const float* __restrict__ b2_in,
    const float* __restrict__ W1_o, const float* __restrict__ b1_o,
    const float* __restrict__ W2_o, const float* __restrict__ b2_o,
    ushort_t* __restrict__ STnext,      // [CDIM][NN] bf16
    float* __restrict__ act) {          // [BB][NA*SIG] fp32
  __shared__ ushort_t Abuf[2][BM * BK];   // 2 x 16 KB
  __shared__ ushort_t Bbuf[2][BN * BK];   // 2 x 16 KB
  __shared__ float ctxs[128 * CTXP];      // 67.6 KB  (total 131.6 KB)

  const int tid = threadIdx.x;
  const int bx = blockIdx.x, by = blockIdx.y;
  const int nbase = by * BN;

  if (bx < 31) {
    // ---------- GEMM with double-buffered, swizzled LDS ----------
    const int mbase = bx * BM;
    const int wave = tid >> 6, lane = tid & 63;
    const int wr = wave >> 1, wc = wave & 1;
    const int r = lane & 15, hi = lane >> 4;

    f32x4 acc[4][4];
#pragma unroll
    for (int i = 0; i < 4; ++i)
#pragma unroll
      for (int j = 0; j < 4; ++j) acc[i][j] = (f32x4){0.f, 0.f, 0.f, 0.f};

    // Staging map (rule-21 swizzle): LDS filled linearly (thread tid -> byte tid*16
    // within each 4KB chunk c). That slot (row = c*32 + tid/8, slot byte (tid&7)*16)
    // holds logical k = 8*((tid&7) ^ ((tid>>3)&7)) after byte ^= ((row&7)<<4).
    const int trow = tid >> 3;                                // 0..31
    const int k0 = ((tid & 7) ^ (trow & 7)) << 3;             // element offset
    const ushort_t* sa[4];
    const ushort_t* sb[4];
#pragma unroll
    for (int c = 0; c < 4; ++c) {
      sa[c] = A   + (size_t)(mbase + c * 32 + trow) * NN + k0;
      sb[c] = Bst + (size_t)(nbase + c * 32 + trow) * NN + k0;
    }
    const int ldst = tid * 8;  // element offset within buf (16B per thread)

    // prologue: stage K-tile 0 into buf 0
#pragma unroll
    for (int c = 0; c < 4; ++c) {
      gll16(sa[c], &Abuf[0][c * 2048 + ldst]);
      gll16(sb[c], &Bbuf[0][c * 2048 + ldst]);
      sa[c] += BK; sb[c] += BK;
    }

    for (int ks = 0; ks < NKS; ++ks) {
      const int cur = ks & 1;
      asm volatile("s_waitcnt vmcnt(0)" ::: "memory");   // buf[cur] loads complete
      __builtin_amdgcn_s_barrier();                      // visible to all waves; also
                                                         // guards buf[cur^1] overwrite
      if (ks + 1 < NKS) {                                // issue next tile -> overlaps MFMA
#pragma unroll
        for (int c = 0; c < 4; ++c) {
          gll16(sa[c], &Abuf[cur ^ 1][c * 2048 + ldst]);
          gll16(sb[c], &Bbuf[cur ^ 1][c * 2048 + ldst]);
          sa[c] += BK; sb[c] += BK;
        }
        asm volatile("" ::: "memory");                   // keep issue before ds_reads
      }

      short8v a[4][2], b[4][2];
#pragma unroll
      for (int mi = 0; mi < 4; ++mi)
#pragma unroll
        for (int kk = 0; kk < 2; ++kk) {
          const int lb = kk * 64 + hi * 16;              // logical byte in row
          const int sw = (lb ^ ((r & 7) << 4)) >> 1;     // physical element offset
          a[mi][kk] = *(const short8v*)&Abuf[cur][(wr * 64 + mi * 16 + r) * BK + sw];
          b[mi][kk] = *(const short8v*)&Bbuf[cur][(wc * 64 + mi * 16 + r) * BK + sw];
        }
#pragma unroll
      for (int mi = 0; mi < 4; ++mi)
#pragma unroll
        for (int ni = 0; ni < 4; ++ni) {
          acc[mi][ni] = __builtin_amdgcn_mfma_f32_16x16x32_bf16(a[mi][0], b[ni][0], acc[mi][ni], 0, 0, 0);
          acc[mi][ni] = __builtin_amdgcn_mfma_f32_16x16x32_bf16(a[mi][1], b[ni][1], acc[mi][ni], 0, 0, 0);
        }
    }

    // acc -> LDS ctx tile (local [neuron][col])
    const int r4 = (hi) * 4, cidx = lane & 15;
#pragma unroll
    for (int mi = 0; mi < 4; ++mi)
#pragma unroll
      for (int ni = 0; ni < 4; ++ni)
#pragma unroll
        for (int v = 0; v < 4; ++v)
          ctxs[(wr * 64 + mi * 16 + r4 + v) * CTXP + wc * 64 + ni * 16 + cidx] = acc[mi][ni][v];
    __syncthreads();

    // ---------- per-neuron MLP epilogue ----------
    const bool is_action = (mbase >= 3584);
    for (int iter = 0; iter < 4; ++iter) {
      const int nr = iter * 32 + (tid >> 3);
      const int bl = tid & 7;
      float cv[SIG];
      const float* cp = ctxs + nr * CTXP + bl * SIG;
#pragma unroll
      for (int d = 0; d < SIG; ++d) cv[d] = cp[d];

      const int no = mbase + nr;
      const float* w1 = W1_o + (size_t)no * HID * SIG;
      const float* b1 = b1_o + (size_t)no * HID;
      float h[HID];
#pragma unroll
      for (int hh = 0; hh < HID; ++hh) {
        float s = b1[hh];
#pragma unroll
        for (int d = 0; d < SIG; ++d) s += w1[hh * SIG + d] * cv[d];
        h[hh] = tanh_fast(s);
      }
      const float* w2 = W2_o + (size_t)no * SIG * HID;
      const float* b2 = b2_o + (size_t)no * SIG;
      float o16[SIG];
#pragma unroll
      for (int d = 0; d < SIG; ++d) {
        float s = b2[d];
#pragma unroll
        for (int hh = 0; hh < HID; ++hh) s += w2[d * HID + hh] * h[hh];
        o16[d] = s;
      }
      if (is_action) {
        float* ap = act + (size_t)(by * 8 + bl) * (NA * SIG) + (size_t)(no - 3584) * SIG;
#pragma unroll
        for (int k = 0; k < 4; ++k)
          *(float4*)(ap + 4 * k) = make_float4(o16[4*k], o16[4*k+1], o16[4*k+2], o16[4*k+3]);
      }
      float* wp = ctxs + nr * CTXP + bl * SIG;
#pragma unroll
      for (int d = 0; d < SIG; ++d) wp[d] = o16[d];
    }
    __syncthreads();
  } else {
    // ---------- input-neuron MLP ----------
    for (int iter = 0; iter < 4; ++iter) {
      const int nr = iter * 32 + (tid >> 3);
      const int bl = tid & 7;
      const int bg = by * 8 + bl;
      const float* xb = x + ((size_t)bg * TT + t) * IN_DIM;
      const float* w1 = W1_in + (size_t)nr * HID * IN_DIM;
      float h[HID];
#pragma unroll
      for (int hh = 0; hh < HID; ++hh) h[hh] = b1_in[nr * HID + hh];
      for (int i = 0; i < IN_DIM; i += 4) {
        const float4 xv = *(const float4*)(xb + i);
#pragma unroll
        for (int hh = 0; hh < HID; ++hh) {
          const float4 wv = *(const float4*)(w1 + hh * IN_DIM + i);
          h[hh] += wv.x * xv.x + wv.y * xv.y + wv.z * xv.z + wv.w * xv.w;
        }
      }
#pragma unroll
      for (int hh = 0; hh < HID; ++hh) h[hh] = tanh_fast(h[hh]);
      const float* w2 = W2_in + (size_t)nr * SIG * HID;
      float o16[SIG];
#pragma unroll
      for (int d = 0; d < SIG; ++d) {
        float s = b2_in[nr * SIG + d];
#pragma unroll
        for (int hh = 0; hh < HID; ++hh) s += w2[d * HID + hh] * h[hh];
        o16[d] = s;
      }
      float* wp = ctxs + nr * CTXP + bl * SIG;
#pragma unroll
      for (int d = 0; d < SIG; ++d) wp[d] = o16[d];
    }
    __syncthreads();
  }

  // ---------- common write-out: ctxs -> STnext bf16 (transposed, 128B stores) ----------
  const int col0 = (bx == 31) ? 0 : NI + bx * BM;
  const int c = tid >> 1, nh = tid & 1;
  const float* colp = ctxs + (size_t)nh * 64 * CTXP + c;
  uint4* dst = (uint4*)(STnext + (size_t)(nbase + c) * NN + col0 + nh * 64);
#pragma unroll
  for (int k = 0; k < 8; ++k) {
    const unsigned w0 = (unsigned)f2b(colp[(k*8+0)*CTXP]) | ((unsigned)f2b(colp[(k*8+1)*CTXP]) << 16);
    const unsigned w1 = (unsigned)f2b(colp[(k*8+2)*CTXP]) | ((unsigned)f2b(colp[(k*8+3)*CTXP]) << 16);
    const unsigned w2 = (unsigned)f2b(colp[(k*8+4)*CTXP]) | ((unsigned)f2b(colp[(k*8+5)*CTXP]) << 16);
    const unsigned w3 = (unsigned)f2b(colp[(k*8+6)*CTXP]) | ((unsigned)f2b(colp[(k*8+7)*CTXP]) << 16);
    dst[k] = make_uint4(w0, w1, w2, w3);
  }
}

// ---------------- per-step output projection (coalesced via WpT) ----------------
__global__ __launch_bounds__(256) void proj_kernel(const float* __restrict__ act,
                                                   const float* __restrict__ WpT,
                                                   const float* __restrict__ bp,
                                                   float* __restrict__ out, int t) {
  const int b = blockIdx.x;
  const int o = threadIdx.x & 63, q = threadIdx.x >> 6;
  const float* a = act + (size_t)b * (NA * SIG) + q * 1536;
  const float* w = WpT + (size_t)q * 1536 * 64 + o;
  float s = 0.f;
  for (int j = 0; j < 1536; j += 4) {
    const float4 av = *(const float4*)(a + j);
    s += av.x * w[(size_t)(j + 0) * 64] + av.y * w[(size_t)(j + 1) * 64]
       + av.z * w[(size_t)(j + 2) * 64] + av.w * w[(size_t)(j + 3) * 64];
  }
  __shared__ float red[4][64];
  red[q][o] = s;
  __syncthreads();
  if (q == 0) {
    const float y = red[0][o] + red[1][o] + red[2][o] + red[3][o] + bp[o];
    out[((size_t)b * TT + t) * OUT_DIM + o] = y;
  }
}

extern "C" void kernel_launch(void* const* d_in, const int* in_sizes, int n_in,
                              void* d_out, int out_size, void* d_ws, size_t ws_size,
                              hipStream_t stream) {
  const float* x     = (const float*)d_in[0];
  const float* W1_in = (const float*)d_in[1];
  const float* b1_in = (const float*)d_in[2];
  const float* W2_in = (const float*)d_in[3];
  const float* b2_in = (const float*)d_in[4];
  const float* W1_o  = (const float*)d_in[5];
  const float* b1_o  = (const float*)d_in[6];
  const float* W2_o  = (const float*)d_in[7];
  const float* b2_o  = (const float*)d_in[8];
  const float* q_all = (const float*)d_in[9];
  const float* k_all = (const float*)d_in[10];
  const float* Wp    = (const float*)d_in[11];
  const float* bp    = (const float*)d_in[12];
  float* out = (float*)d_out;

  char* p = (char*)d_ws;
  ushort_t* Abf = (ushort_t*)p; p += (size_t)NO * NN * 2;       // 32.5 MB
  ushort_t* ST0 = (ushort_t*)p; p += (size_t)CDIM * NN * 2;     // 8.4 MB
  ushort_t* ST1 = (ushort_t*)p; p += (size_t)CDIM * NN * 2;     // 8.4 MB
  float*    act = (float*)p;    p += (size_t)BB * NA * SIG * 4; // 1.6 MB
  float*    WpT = (float*)p;    p += (size_t)NA * SIG * OUT_DIM * 4; // 1.6 MB

  hipMemsetAsync(ST0, 0, (size_t)CDIM * NN * 2, stream);        // prev0 = 0
  attn_kernel<<<NO, 256, 0, stream>>>(q_all, k_all, Abf);
  wpt_kernel<<<(NA * SIG) / 64, 256, 0, stream>>>(Wp, WpT);

  for (int t = 0; t < TT; ++t) {
    ushort_t* prev = (t & 1) ? ST1 : ST0;
    ushort_t* next = (t & 1) ? ST0 : ST1;
    dim3 grid(32, CDIM / BN);  // 32 x 8 = 256 blocks = 1/CU
    fused_step_kernel<<<grid, 256, 0, stream>>>(Abf, prev, x, t,
                                                W1_in, b1_in, W2_in, b2_in,
                                                W1_o, b1_o, W2_o, b2_o, next, act);
    proj_kernel<<<BB, 256, 0, stream>>>(act, WpT, bp, out, t);
  }
}

// Round 9
// 6075.599 us; speedup vs baseline: 1.7105x; 1.0110x over previous
//
#include <hip/hip_runtime.h>
#include <hip/hip_bf16.h>

// IntelligentNetwork on MI355X — fused step kernel, A/B on prefetch depth.
// Even t: PF=2 (3-buffer LDS, counted vmcnt(8), 64KB in flight per CU).
// Odd  t: PF=0 (same code, vmcnt(0) drain == R8 depth-1 semantics).
// Shared: XCD swizzle (same-bx blocks -> same XCD L2), 2-pass MLP epilogue.

#define NI 128
#define NTR 3584
#define NA 384
#define NN 4096
#define NO (NN - NI)        // 3968 = 31*128
#define HID 32
#define KQ 16
#define SIG 16
#define IN_DIM 128
#define OUT_DIM 64
#define BB 64
#define TT 32
#define CDIM (BB * SIG)     // 1024

#define BM 128
#define BN 128
#define BK 64
#define NKS (NN / BK)       // 64 K-steps
#define CTXP 132            // padded LDS row stride (floats)

typedef unsigned short ushort_t;
typedef __attribute__((ext_vector_type(8))) short short8v;
typedef __attribute__((ext_vector_type(4))) float f32x4;

__device__ inline ushort_t f2b(float f) {
  __hip_bfloat16 h = __float2bfloat16(f);
  return *reinterpret_cast<ushort_t*>(&h);
}

__device__ inline float tanh_fast(float s) {
  const float e = __expf(2.f * s);
  return 1.f - 2.f / (e + 1.f);
}

__device__ inline void gll16(const void* g, void* l) {
  __builtin_amdgcn_global_load_lds(
      (const __attribute__((address_space(1))) unsigned int*)g,
      (__attribute__((address_space(3))) unsigned int*)l, 16, 0, 0);
}

// ---------------- attention matrix (once per launch) ----------------
__global__ __launch_bounds__(256) void attn_kernel(const float* __restrict__ q_all,
                                                   const float* __restrict__ k_all,
                                                   ushort_t* __restrict__ A) {
  const int row = blockIdx.x;
  const int n = NI + row;
  float q[KQ];
#pragma unroll
  for (int i = 0; i < KQ; ++i) q[i] = q_all[n * KQ + i];

  float e[16];
  float local = 0.f;
#pragma unroll
  for (int j = 0; j < 16; ++j) {
    const int m = j * 256 + threadIdx.x;
    const float* kr = k_all + (size_t)m * KQ;
    float s = 0.f;
#pragma unroll
    for (int i = 0; i < KQ; ++i) s += q[i] * kr[i];
    e[j] = __expf(s * 0.25f);
    local += e[j];
  }
  __shared__ float red[256];
  red[threadIdx.x] = local;
  __syncthreads();
  for (int off = 128; off > 0; off >>= 1) {
    if (threadIdx.x < off) red[threadIdx.x] += red[threadIdx.x + off];
    __syncthreads();
  }
  const float inv = 1.f / red[0];
#pragma unroll
  for (int j = 0; j < 16; ++j) {
    const int m = j * 256 + threadIdx.x;
    A[(size_t)row * NN + m] = f2b(e[j] * inv);
  }
}

// ---------------- Wp transpose (once): WpT[j][o] = Wp[o][j] ----------------
__global__ __launch_bounds__(256) void wpt_kernel(const float* __restrict__ Wp,
                                                  float* __restrict__ WpT) {
  __shared__ float tile[64][65];
  const int j0 = blockIdx.x * 64;
  const int tx = threadIdx.x & 63, ty = threadIdx.x >> 6;
#pragma unroll
  for (int oo = ty; oo < 64; oo += 4)
    tile[oo][tx] = Wp[(size_t)oo * (NA * SIG) + j0 + tx];
  __syncthreads();
#pragma unroll
  for (int oo = ty; oo < 64; oo += 4)
    WpT[(size_t)(j0 + oo) * 64 + tx] = tile[tx][oo];
}

// ---------------- fused per-step kernel (templated on prefetch depth) ----------------
template<int PF>
__global__ __launch_bounds__(256) void fused_step_kernel(
    const ushort_t* __restrict__ A,     // [NO][NN] bf16 attn
    const ushort_t* __restrict__ Bst,   // ST_prev [CDIM][NN] bf16
    const float* __restrict__ x, int t,
    const float* __restrict__ W1_in, const float* __restrict__ b1_in,
    const float* __restrict__ W2_in, const float* __restrict__ b2_in,
    const float* __restrict__ W1_o, const float* __restrict__ b1_o,
    const float* __restrict__ W2_o, const float* __restrict__ b2_o,
    ushort_t* __restrict__ STnext,      // [CDIM][NN] bf16
    float* __restrict__ act) {          // [BB][NA*SIG] fp32
  __shared__ ushort_t Abuf[3][BM * BK];   // 3 x 16 KB
  __shared__ ushort_t Bbuf[3][BN * BK];   // 3 x 16 KB
  __shared__ float ctxs[64 * CTXP];       // 33.8 KB  (total 129.8 KB)

  const int tid = threadIdx.x;
  // XCD swizzle: blocks sharing bx (A-tile + weight slice) land on one XCD (bid%8).
  const int L = blockIdx.x;                       // 0..255
  const int bx = (L & 7) | ((L >> 6) << 3);       // 0..31
  const int by = (L >> 3) & 7;                    // 0..7
  const int nbase = by * BN;
  const int mbase = bx * BM;

  f32x4 acc[4][4];
  const int wave = tid >> 6, lane = tid & 63;
  const int wr = wave >> 1, wc = wave & 1;
  const int r = lane & 15, hi = lane >> 4;

  if (bx < 31) {
    // ---------- GEMM: 3-buffer pipelined, swizzled LDS ----------
#pragma unroll
    for (int i = 0; i < 4; ++i)
#pragma unroll
      for (int j = 0; j < 4; ++j) acc[i][j] = (f32x4){0.f, 0.f, 0.f, 0.f};

    // staging source swizzle (rule-21): physical slot (tid&7) of row trow holds
    // logical k-chunk ((tid&7) ^ (trow&7)); read side XORs back.
    const int trow = tid >> 3;                      // 0..31
    const int k0 = ((tid & 7) ^ (trow & 7)) << 3;   // element offset in row
    const ushort_t* sa[4];
    const ushort_t* sb[4];
#pragma unroll
    for (int c = 0; c < 4; ++c) {
      sa[c] = A   + (size_t)(mbase + c * 32 + trow) * NN + k0;
      sb[c] = Bst + (size_t)(nbase + c * 32 + trow) * NN + k0;
    }
    const int ldst = tid * 8;

    auto stage = [&](int tile, int buf) {
#pragma unroll
      for (int c = 0; c < 4; ++c) {
        gll16(sa[c] + (size_t)tile * BK, &Abuf[buf][c * 2048 + ldst]);
        gll16(sb[c] + (size_t)tile * BK, &Bbuf[buf][c * 2048 + ldst]);
      }
    };

    stage(0, 0);
    stage(1, 1);

    for (int ks = 0; ks < NKS; ++ks) {
      const int cur = ks % 3;
      if (PF == 2 && ks < NKS - 1) {
        asm volatile("s_waitcnt vmcnt(8)" ::: "memory");   // tile ks done; ks+1 in flight
      } else {
        asm volatile("s_waitcnt vmcnt(0)" ::: "memory");   // full drain (B-arm / last iter)
      }
      __builtin_amdgcn_s_barrier();
      if (ks + 2 < NKS) {
        stage(ks + 2, (ks + 2) % 3);
        asm volatile("" ::: "memory");
      }

      short8v a[4][2], b[4][2];
#pragma unroll
      for (int mi = 0; mi < 4; ++mi)
#pragma unroll
        for (int kk = 0; kk < 2; ++kk) {
          const int lb = kk * 64 + hi * 16;                // logical byte in row
          const int sw = (lb ^ ((r & 7) << 4)) >> 1;       // physical element offset
          a[mi][kk] = *(const short8v*)&Abuf[cur][(wr * 64 + mi * 16 + r) * BK + sw];
          b[mi][kk] = *(const short8v*)&Bbuf[cur][(wc * 64 + mi * 16 + r) * BK + sw];
        }
#pragma unroll
      for (int mi = 0; mi < 4; ++mi)
#pragma unroll
        for (int ni = 0; ni < 4; ++ni) {
          acc[mi][ni] = __builtin_amdgcn_mfma_f32_16x16x32_bf16(a[mi][0], b[ni][0], acc[mi][ni], 0, 0, 0);
          acc[mi][ni] = __builtin_amdgcn_mfma_f32_16x16x32_bf16(a[mi][1], b[ni][1], acc[mi][ni], 0, 0, 0);
        }
    }
  }

  // ---------- two passes: 64 neurons each (fits ctxs in LDS with 3-buf GEMM) ----------
  const bool is_gemm = (bx < 31);
  const bool is_action = (mbase >= 3584);
  const int col0 = is_gemm ? NI + mbase : 0;

#pragma unroll
  for (int p = 0; p < 2; ++p) {
    if (p) __syncthreads();              // protect ctxs reuse between passes
    if (is_gemm) {
      if (wr == p) {                     // waves owning rows p*64..p*64+63 dump acc
        const int r4 = hi * 4, cidx = lane & 15;
#pragma unroll
        for (int mi = 0; mi < 4; ++mi)
#pragma unroll
          for (int ni = 0; ni < 4; ++ni)
#pragma unroll
            for (int v = 0; v < 4; ++v)
              ctxs[(mi * 16 + r4 + v) * CTXP + wc * 64 + ni * 16 + cidx] = acc[mi][ni][v];
      }
      __syncthreads();
      // MLP: 64 neurons x 8 batches, 2 tasks/thread
#pragma unroll
      for (int it = 0; it < 2; ++it) {
        const int nr = it * 32 + (tid >> 3);   // local neuron 0..63
        const int bl = tid & 7;
        float cv[SIG];
        const float* cp = ctxs + nr * CTXP + bl * SIG;
#pragma unroll
        for (int d = 0; d < SIG; ++d) cv[d] = cp[d];

        const int no = mbase + p * 64 + nr;
        const float* w1 = W1_o + (size_t)no * HID * SIG;
        const float* b1 = b1_o + (size_t)no * HID;
        float h[HID];
#pragma unroll
        for (int hh = 0; hh < HID; ++hh) {
          float s = b1[hh];
#pragma unroll
          for (int d = 0; d < SIG; ++d) s += w1[hh * SIG + d] * cv[d];
          h[hh] = tanh_fast(s);
        }
        const float* w2 = W2_o + (size_t)no * SIG * HID;
        const float* b2 = b2_o + (size_t)no * SIG;
        float o16[SIG];
#pragma unroll
        for (int d = 0; d < SIG; ++d) {
          float s = b2[d];
#pragma unroll
          for (int hh = 0; hh < HID; ++hh) s += w2[d * HID + hh] * h[hh];
          o16[d] = s;
        }
        if (is_action) {
          float* ap = act + (size_t)(by * 8 + bl) * (NA * SIG) + (size_t)(no - 3584) * SIG;
#pragma unroll
          for (int k = 0; k < 4; ++k)
            *(float4*)(ap + 4 * k) = make_float4(o16[4*k], o16[4*k+1], o16[4*k+2], o16[4*k+3]);
        }
        float* wp = ctxs + nr * CTXP + bl * SIG;
#pragma unroll
        for (int d = 0; d < SIG; ++d) wp[d] = o16[d];
      }
    } else {
      // input-neuron MLP: 64 neurons x 8 batches per pass
      __syncthreads();
#pragma unroll
      for (int it = 0; it < 2; ++it) {
        const int nr = it * 32 + (tid >> 3);
        const int bl = tid & 7;
        const int bg = by * 8 + bl;
        const int ng = p * 64 + nr;
        const float* xb = x + ((size_t)bg * TT + t) * IN_DIM;
        const float* w1 = W1_in + (size_t)ng * HID * IN_DIM;
        float h[HID];
#pragma unroll
        for (int hh = 0; hh < HID; ++hh) h[hh] = b1_in[ng * HID + hh];
        for (int i = 0; i < IN_DIM; i += 4) {
          const float4 xv = *(const float4*)(xb + i);
#pragma unroll
          for (int hh = 0; hh < HID; ++hh) {
            const float4 wv = *(const float4*)(w1 + hh * IN_DIM + i);
            h[hh] += wv.x * xv.x + wv.y * xv.y + wv.z * xv.z + wv.w * xv.w;
          }
        }
#pragma unroll
        for (int hh = 0; hh < HID; ++hh) h[hh] = tanh_fast(h[hh]);
        const float* w2 = W2_in + (size_t)ng * SIG * HID;
        float o16[SIG];
#pragma unroll
        for (int d = 0; d < SIG; ++d) {
          float s = b2_in[ng * SIG + d];
#pragma unroll
          for (int hh = 0; hh < HID; ++hh) s += w2[d * HID + hh] * h[hh];
          o16[d] = s;
        }
        float* wp = ctxs + nr * CTXP + bl * SIG;
#pragma unroll
        for (int d = 0; d < SIG; ++d) wp[d] = o16[d];
      }
    }
    __syncthreads();
    // write-out pass p: ctxs[j][c] -> STnext[nbase+c][col0 + p*64 + j], 64B/thread
    {
      const int c = tid >> 1, half = tid & 1;
      const float* colp = ctxs + (size_t)(half * 32) * CTXP + c;
      uint4* dst = (uint4*)(STnext + (size_t)(nbase + c) * NN + col0 + p * 64 + half * 32);
#pragma unroll
      for (int k = 0; k < 4; ++k) {
        const unsigned w0 = (unsigned)f2b(colp[(k*8+0)*CTXP]) | ((unsigned)f2b(colp[(k*8+1)*CTXP]) << 16);
        const unsigned w1 = (unsigned)f2b(colp[(k*8+2)*CTXP]) | ((unsigned)f2b(colp[(k*8+3)*CTXP]) << 16);
        const unsigned w2 = (unsigned)f2b(colp[(k*8+4)*CTXP]) | ((unsigned)f2b(colp[(k*8+5)*CTXP]) << 16);
        const unsigned w3 = (unsigned)f2b(colp[(k*8+6)*CTXP]) | ((unsigned)f2b(colp[(k*8+7)*CTXP]) << 16);
        dst[k] = make_uint4(w0, w1, w2, w3);
      }
    }
  }
}

// ---------------- per-step output projection (coalesced via WpT) ----------------
__global__ __launch_bounds__(256) void proj_kernel(const float* __restrict__ act,
                                                   const float* __restrict__ WpT,
                                                   const float* __restrict__ bp,
                                                   float* __restrict__ out, int t) {
  const int b = blockIdx.x;
  const int o = threadIdx.x & 63, q = threadIdx.x >> 6;
  const float* a = act + (size_t)b * (NA * SIG) + q * 1536;
  const float* w = WpT + (size_t)q * 1536 * 64 + o;
  float s = 0.f;
  for (int j = 0; j < 1536; j += 4) {
    const float4 av = *(const float4*)(a + j);
    s += av.x * w[(size_t)(j + 0) * 64] + av.y * w[(size_t)(j + 1) * 64]
       + av.z * w[(size_t)(j + 2) * 64] + av.w * w[(size_t)(j + 3) * 64];
  }
  __shared__ float red[4][64];
  red[q][o] = s;
  __syncthreads();
  if (q == 0) {
    const float y = red[0][o] + red[1][o] + red[2][o] + red[3][o] + bp[o];
    out[((size_t)b * TT + t) * OUT_DIM + o] = y;
  }
}

extern "C" void kernel_launch(void* const* d_in, const int* in_sizes, int n_in,
                              void* d_out, int out_size, void* d_ws, size_t ws_size,
                              hipStream_t stream) {
  const float* x     = (const float*)d_in[0];
  const float* W1_in = (const float*)d_in[1];
  const float* b1_in = (const float*)d_in[2];
  const float* W2_in = (const float*)d_in[3];
  const float* b2_in = (const float*)d_in[4];
  const float* W1_o  = (const float*)d_in[5];
  const float* b1_o  = (const float*)d_in[6];
  const float* W2_o  = (const float*)d_in[7];
  const float* b2_o  = (const float*)d_in[8];
  const float* q_all = (const float*)d_in[9];
  const float* k_all = (const float*)d_in[10];
  const float* Wp    = (const float*)d_in[11];
  const float* bp    = (const float*)d_in[12];
  float* out = (float*)d_out;

  char* p = (char*)d_ws;
  ushort_t* Abf = (ushort_t*)p; p += (size_t)NO * NN * 2;       // 32.5 MB
  ushort_t* ST0 = (ushort_t*)p; p += (size_t)CDIM * NN * 2;     // 8.4 MB
  ushort_t* ST1 = (ushort_t*)p; p += (size_t)CDIM * NN * 2;     // 8.4 MB
  float*    act = (float*)p;    p += (size_t)BB * NA * SIG * 4; // 1.6 MB
  float*    WpT = (float*)p;    p += (size_t)NA * SIG * OUT_DIM * 4; // 1.6 MB

  hipMemsetAsync(ST0, 0, (size_t)CDIM * NN * 2, stream);        // prev0 = 0
  attn_kernel<<<NO, 256, 0, stream>>>(q_all, k_all, Abf);
  wpt_kernel<<<(NA * SIG) / 64, 256, 0, stream>>>(Wp, WpT);

  for (int t = 0; t < TT; ++t) {
    ushort_t* prev = (t & 1) ? ST1 : ST0;
    ushort_t* next = (t & 1) ? ST0 : ST1;
    if ((t & 1) == 0)
      fused_step_kernel<2><<<256, 256, 0, stream>>>(Abf, prev, x, t,
                                                    W1_in, b1_in, W2_in, b2_in,
                                                    W1_o, b1_o, W2_o, b2_o, next, act);
    else
      fused_step_kernel<0><<<256, 256, 0, stream>>>(Abf, prev, x, t,
                                                    W1_in, b1_in, W2_in, b2_in,
                                                    W1_o, b1_o, W2_o, b2_o, next, act);
    proj_kernel<<<BB, 256, 0, stream>>>(act, WpT, bp, out, t);
  }
}